// Round 4
// baseline (751.515 us; speedup 1.0000x reference)
//
#include <hip/hip_runtime.h>

typedef unsigned short ushortT;
typedef unsigned short us2 __attribute__((ext_vector_type(2)));
typedef unsigned short us4 __attribute__((ext_vector_type(4)));
typedef short s4 __attribute__((ext_vector_type(4)));
typedef short s8 __attribute__((ext_vector_type(8)));
typedef float f4 __attribute__((ext_vector_type(4)));

__device__ __forceinline__ float bf2f(ushortT u) {
  union { unsigned u; float f; } x; x.u = ((unsigned)u) << 16; return x.f;
}
__device__ __forceinline__ ushortT f2bf(float f) {
  union { float f; unsigned u; } x; x.f = f;
  unsigned r = x.u + 0x7fffu + ((x.u >> 16) & 1u);
  return (ushortT)(r >> 16);
}
__device__ __forceinline__ ushortT bftrunc(float f) {
  union { float f; unsigned u; } x; x.f = f;
  return (ushortT)(x.u >> 16);
}
__device__ __forceinline__ s4 lo4(s8 v) { return __builtin_shufflevector(v, v, 0, 1, 2, 3); }
__device__ __forceinline__ s4 hi4(s8 v) { return __builtin_shufflevector(v, v, 4, 5, 6, 7); }
__device__ __forceinline__ s8 cat(s4 a, s4 b) { return __builtin_shufflevector(a, b, 0, 1, 2, 3, 4, 5, 6, 7); }

// async global->LDS, 16B per lane; lds dest must be wave-uniform base (lane*16 implicit)
__device__ __forceinline__ void gld16(const ushortT* g, ushortT* l) {
  __builtin_amdgcn_global_load_lds(
      (const __attribute__((address_space(1))) void*)g,
      (__attribute__((address_space(3))) void*)l, 16, 0, 0);
}

// ---------- prep: x fp32->bf16, weight transposes (concat QKV), bias concat ----------
// W2 is stored phi32-permuted along K (phi(t*16+c)=c*2+t within each 32-chunk)
// so the fused FFN can consume h packed with the same permutation
// (contraction-invariant; identical to attn's V^T pcol trick).
#define CONV_BLOCKS 15600   // 62400*256/4/256
__global__ void prep(const float* __restrict__ x,
                     const float* __restrict__ Wq, const float* __restrict__ Wk,
                     const float* __restrict__ Wv, const float* __restrict__ Wo,
                     const float* __restrict__ W1, const float* __restrict__ W2,
                     const float* __restrict__ bq, const float* __restrict__ bk,
                     const float* __restrict__ bv,
                     ushortT* __restrict__ xb, ushortT* __restrict__ WqkvT,
                     ushortT* __restrict__ WoT, ushortT* __restrict__ W1T,
                     ushortT* __restrict__ W2P, float* __restrict__ bqkv)
{
  if (blockIdx.x < CONV_BLOCKS) {
    size_t base = ((size_t)blockIdx.x * 256 + threadIdx.x) * 4;
    f4 v = *(const f4*)(x + base);
    us4 o; o[0]=f2bf(v[0]); o[1]=f2bf(v[1]); o[2]=f2bf(v[2]); o[3]=f2bf(v[3]);
    *(us4*)(xb + base) = o;
    return;
  }
  long e = (long)(blockIdx.x - CONV_BLOCKS) * 256 + threadIdx.x;
  if (e < 196608) {                       // Wq|Wk|Wv -> WqkvT (768x256)
    int seg = e >> 16; int p = e & 65535; int r = p >> 8, c = p & 255;
    const float* W = seg == 0 ? Wq : (seg == 1 ? Wk : Wv);
    WqkvT[(size_t)(seg * 256 + c) * 256 + r] = f2bf(W[p]);
  } else if (e < 262144) {                // Wo -> WoT (256x256)
    int p = e - 196608; int r = p >> 8, c = p & 255;
    WoT[(size_t)c * 256 + r] = f2bf(Wo[p]);
  } else if (e < 786432) {                // W1 (256x2048) -> W1T (2048x256)
    int p = e - 262144; int r = p >> 11, c = p & 2047;
    W1T[(size_t)c * 256 + r] = f2bf(W1[p]);
  } else if (e < 1310720) {               // W2 (2048x256) -> W2P (256x2048, phi32 on k)
    int p = e - 786432; int r = p >> 8, c = p & 255;
    int rp = (r & ~31) | ((r & 15) << 1) | ((r >> 4) & 1);
    W2P[(size_t)c * 2048 + rp] = f2bf(W2[p]);
  } else {                                // bq|bk|bv -> bqkv (768 fp32)
    int p = (int)(e - 1310720);
    const float* b = (p >> 8) == 0 ? bq : ((p >> 8) == 1 ? bk : bv);
    bqkv[p] = b[p & 255];
  }
}
#define PREP_BLOCKS (CONV_BLOCKS + 5123)

// ---------- GEMM, 2-deep dbuf pipeline w/ counted vmcnt (T3/T4-minimal) ----------
#define BM 128
#define BN 128
#define BK 32

template <typename CT>
__global__ __launch_bounds__(256, 4) void gemm_async(
    const ushortT* __restrict__ A, const ushortT* __restrict__ Bt,
    const float* __restrict__ bias,
    CT* __restrict__ O0, CT* __restrict__ O1, CT* __restrict__ O2,
    int M, int N, int K, int relu, int route, float s0)
{
  __shared__ ushortT As[2][BM * BK];
  __shared__ ushortT Bs[2][BN * BK];
  const int tileN = blockIdx.x * BN;
  const int tileM = blockIdx.y * BM;
  const int tid  = threadIdx.x;
  const int wave = tid >> 6, lane = tid & 63;
  const int wm = (wave >> 1) * 64, wn = (wave & 1) * 64;
  const int lrow = lane & 15;
  const int kq = (lane >> 4) * 8;
  const int crow0 = (lane >> 4) * 4;
  const int ccol  = lane & 15;

  const int srow = wave * 16 + (lane >> 2);
  const int scol = (lane & 3) * 8;
  int ar0 = tileM + srow;        if (ar0 > M - 1) ar0 = M - 1;
  int ar1 = tileM + 64 + srow;   if (ar1 > M - 1) ar1 = M - 1;
  const ushortT* ap0 = A + (size_t)ar0 * K + scol;
  const ushortT* ap1 = A + (size_t)ar1 * K + scol;
  const ushortT* bp0 = Bt + (size_t)(tileN + srow) * K + scol;
  const ushortT* bp1 = Bt + (size_t)(tileN + 64 + srow) * K + scol;
  const int d0 = wave * 512;        // wave-uniform LDS dest offsets
  const int d1 = 2048 + wave * 512;

  // bias preload BEFORE any staging; keep-alive forces retire so in-loop
  // vmcnt counting sees only gld16 ops.
  float bvv[4];
#pragma unroll
  for (int ni = 0; ni < 4; ni++) bvv[ni] = bias[tileN + wn + ni * 16 + ccol];
  asm volatile("" :: "v"(bvv[0]), "v"(bvv[1]), "v"(bvv[2]), "v"(bvv[3]));

  f4 acc[4][4];
#pragma unroll
  for (int i = 0; i < 4; i++)
#pragma unroll
    for (int j = 0; j < 4; j++) acc[i][j] = 0.f;

  // prologue: stage tiles 0 and 1
  gld16(ap0, As[0] + d0); gld16(ap1, As[0] + d1);
  gld16(bp0, Bs[0] + d0); gld16(bp1, Bs[0] + d1);
  ap0 += BK; ap1 += BK; bp0 += BK; bp1 += BK;
  if (BK < K) {
    gld16(ap0, As[1] + d0); gld16(ap1, As[1] + d1);
    gld16(bp0, Bs[1] + d0); gld16(bp1, Bs[1] + d1);
    ap0 += BK; ap1 += BK; bp0 += BK; bp1 += BK;
  }

  int cur = 0;
  for (int k0 = 0; k0 < K; k0 += BK, cur ^= 1) {
    if (k0 + BK < K) asm volatile("s_waitcnt vmcnt(4)" ::: "memory");
    else             asm volatile("s_waitcnt vmcnt(0)" ::: "memory");
    __builtin_amdgcn_s_barrier();
    __builtin_amdgcn_sched_barrier(0);

    s8 af[4], bfr[4];
#pragma unroll
    for (int mi = 0; mi < 4; mi++)
      af[mi] = *(const s8*)(&As[cur][(wm + mi * 16 + lrow) * BK + kq]);
#pragma unroll
    for (int ni = 0; ni < 4; ni++)
      bfr[ni] = *(const s8*)(&Bs[cur][(wn + ni * 16 + lrow) * BK + kq]);
#pragma unroll
    for (int mi = 0; mi < 4; mi++)
#pragma unroll
      for (int ni = 0; ni < 4; ni++)
        acc[mi][ni] = __builtin_amdgcn_mfma_f32_16x16x32_bf16(af[mi], bfr[ni], acc[mi][ni], 0, 0, 0);

    __builtin_amdgcn_s_barrier();   // all waves done reading buf cur
    __builtin_amdgcn_sched_barrier(0);
    if (k0 + 2 * BK < K) {          // restage into the buffer just consumed
      gld16(ap0, As[cur] + d0); gld16(ap1, As[cur] + d1);
      gld16(bp0, Bs[cur] + d0); gld16(bp1, Bs[cur] + d1);
      ap0 += BK; ap1 += BK; bp0 += BK; bp1 += BK;
    }
  }

  CT* dst; int col0, ostride;
  float oscale = 1.f;
  if (route) {
    int seg = tileN >> 8;
    dst = seg == 0 ? O0 : (seg == 1 ? O1 : O2);
    col0 = tileN & 255; ostride = 256;
    if (seg == 0) oscale = s0;
  } else {
    dst = O0; col0 = tileN; ostride = N;
  }
#pragma unroll
  for (int mi = 0; mi < 4; mi++) {
#pragma unroll
    for (int ni = 0; ni < 4; ni++) {
      int lcol = wn + ni * 16 + ccol;
#pragma unroll
      for (int r = 0; r < 4; r++) {
        int grow = tileM + wm + mi * 16 + crow0 + r;
        if (grow < M) {
          float v = (acc[mi][ni][r] + bvv[ni]) * oscale;
          if (relu) v = fmaxf(v, 0.f);
          if constexpr (sizeof(CT) == 2)
            dst[(size_t)grow * ostride + col0 + lcol] = f2bf(v);
          else
            dst[(size_t)grow * ostride + col0 + lcol] = v;
        }
      }
    }
  }
}

// ---------- MFMA attention, shuffle-free softmax ----------
#define NQ 325
#define NPAD 384
#define KSTR 36      // 72B rows: dword-stride 18 -> 4-way banks, b64-aligned
#define VSTR 388     // 776B rows: dword-stride 194 -> 4-way banks, b64-aligned
#define PSTR 72      // 144B rows: b128-aligned A-frag reads

__global__ __launch_bounds__(256, 2) void attn_mfma(
    const ushortT* __restrict__ q, const ushortT* __restrict__ k,
    const ushortT* __restrict__ v, ushortT* __restrict__ out)
{
  __shared__ ushortT ks[NPAD * KSTR];        // 27648 B
  __shared__ ushortT vt[32 * VSTR];          // 24832 B
  __shared__ ushortT ps[4 * 16 * PSTR];      //  9216 B  (61696 total -> 2 blocks/CU)
  const int bs = blockIdx.x >> 3;
  const int h  = blockIdx.x & 7;
  const size_t rowbase = (size_t)bs * NQ;
  const int hcol = h * 32;
  const int tid = threadIdx.x;
  const int wave = tid >> 6, lane = tid & 63;
  const int g = lane >> 4;
  const int c = lane & 15;

  for (int idx = tid; idx < NPAD * 4; idx += 256) {
    int row = idx >> 2, part = idx & 3;
    s8 kv = 0, vv = 0;
    if (row < NQ) {
      kv = *(const s8*)(k + (rowbase + row) * 256 + hcol + part * 8);
      vv = *(const s8*)(v + (rowbase + row) * 256 + hcol + part * 8);
    }
    *(s4*)(ks + row * KSTR + part * 8)     = lo4(kv);
    *(s4*)(ks + row * KSTR + part * 8 + 4) = hi4(kv);
    int pcol = (row & ~63) | ((row & 15) << 2) | ((row >> 4) & 3);
#pragma unroll
    for (int j = 0; j < 8; j++)
      vt[(part * 8 + j) * VSTR + pcol] = (ushortT)vv[j];
  }
  __syncthreads();

  s8 ones;
#pragma unroll
  for (int j = 0; j < 8; j++) ones[j] = (short)0x3F80;   // bf16 1.0

  ushortT* psw = ps + wave * 16 * PSTR;

  for (int strip = wave; strip < 21; strip += 4) {
    const int m0 = strip * 16;
    s8 qf = 0;
    {
      int qrow = m0 + c;
      if (qrow < NQ) qf = *(const s8*)(q + (rowbase + qrow) * 256 + hcol + g * 8);
    }
    f4 ov0 = 0.f, ov1 = 0.f, ovs = 0.f;

    for (int ch = 0; ch < 6; ++ch) {
      const int nbase = ch * 64;
      f4 sc[4];
#pragma unroll
      for (int t = 0; t < 4; ++t) {
        const ushortT* kr = ks + (nbase + t * 16 + c) * KSTR + g * 8;
        s8 kf = cat(*(const s4*)kr, *(const s4*)(kr + 4));
        f4 z = 0.f;
        sc[t] = __builtin_amdgcn_mfma_f32_16x16x32_bf16(qf, kf, z, 0, 0, 0);
      }
#pragma unroll
      for (int t = 0; t < 4; ++t)
#pragma unroll
        for (int r = 0; r < 4; ++r)
          sc[t][r] = __expf(sc[t][r]);
      if (ch == 5) {
#pragma unroll
        for (int t = 0; t < 4; ++t) {
          bool valid = (t == 0) && (c < 5);   // keys 320..324
#pragma unroll
          for (int r = 0; r < 4; ++r)
            if (!valid) sc[t][r] = 0.f;
        }
      }
#pragma unroll
      for (int r = 0; r < 4; ++r) {
        us4 pw;
#pragma unroll
        for (int t = 0; t < 4; ++t) pw[t] = bftrunc(sc[t][r]);
        *(us4*)(psw + (g * 4 + r) * PSTR + c * 4) = pw;
      }
#pragma unroll
      for (int kt = 0; kt < 2; ++kt) {
        s8 pf = *(const s8*)(psw + c * PSTR + kt * 32 + g * 8);
        ovs = __builtin_amdgcn_mfma_f32_16x16x32_bf16(pf, ones, ovs, 0, 0, 0);
        const ushortT* vr0 = vt + c * VSTR + nbase + kt * 32 + g * 8;
        const ushortT* vr1 = vt + (16 + c) * VSTR + nbase + kt * 32 + g * 8;
        s8 vf0 = cat(*(const s4*)vr0, *(const s4*)(vr0 + 4));
        s8 vf1 = cat(*(const s4*)vr1, *(const s4*)(vr1 + 4));
        ov0 = __builtin_amdgcn_mfma_f32_16x16x32_bf16(pf, vf0, ov0, 0, 0, 0);
        ov1 = __builtin_amdgcn_mfma_f32_16x16x32_bf16(pf, vf1, ov1, 0, 0, 0);
      }
    }
#pragma unroll
    for (int r = 0; r < 4; ++r) {
      int gm = m0 + g * 4 + r;
      if (gm < NQ) {
        float inv = 1.f / ovs[r];
        out[(rowbase + gm) * 256 + hcol + c]      = f2bf(ov0[r] * inv);
        out[(rowbase + gm) * 256 + hcol + 16 + c] = f2bf(ov1[r] * inv);
      }
    }
  }
}

// ---------- fused FFN v4: F-chunk=32, 2 blocks/CU for overlap ----------
// R3 post-mortem: W2-to-regs serialized mid-chunk; reverted to R2's LDS scheme.
// R2 diagnosis: 150 KB LDS -> 1 block/CU -> 2 waves/SIMD -> LDS reads, MFMA,
// VALU and barriers serialize. Fix: halve the F-chunk so LDS = 2x16(W1) +
// 2x16(W2) + 10(hs) + 4(b1) = 78 KB -> 2 blocks/CU (16 waves, 4/SIMD),
// enforced by __launch_bounds__(512,4) (VGPR<=128; R2 measured 108).
// Same per-FLOP LDS/MFMA ratios; 488 blocks now co-resident in ONE round.
//   h-stage : 4m x 2f grid, wave = 32 rows x 16 f (W1 frags reused 2x)
//   W2-stage: 2m x 4n grid, wave = 64 rows x 64 cols, acc[4][4], single kt
#define FCH 32
#define HSTR3 40   // 80B rows: b128-aligned h A-frag reads, 4-bank row shift

__global__ __launch_bounds__(512, 4) void ffn_fused(
    const ushortT* __restrict__ y, const ushortT* __restrict__ W1T,
    const float* __restrict__ b1, const ushortT* __restrict__ W2P,
    const float* __restrict__ b2, float* __restrict__ outp, int M)
{
  __shared__ ushortT w1c[2][32 * 256];    // 2 x 16 KB
  __shared__ ushortT w2c[2][256 * 32];    // 2 x 16 KB
  __shared__ ushortT hs[128 * HSTR3];     // 10 KB
  __shared__ ushortT b1l[2048];           // 4 KB   (total ~78 KB -> 2 blocks/CU)

  const int tid = threadIdx.x;
  const int w = tid >> 6, lane = tid & 63;
  const int g = lane >> 4, c = lane & 15;
  const int rq = w >> 1, fh = w & 1;      // h-stage: rows rq*32+, f-frag fh
  const int mq2 = w >> 2, nq = w & 3;     // W2-stage: rows mq2*64+, cols nq*64+
  const int Mtile = blockIdx.x * 128;

  // b1 -> LDS as bf16
  {
    f4 bv = *(const f4*)(b1 + tid * 4);
    us4 o; o[0]=f2bf(bv[0]); o[1]=f2bf(bv[1]); o[2]=f2bf(bv[2]); o[3]=f2bf(bv[3]);
    *(us4*)(b1l + tid * 4) = o;
  }

  // prestage chunk 0 (2+2 gld16 per thread)
#pragma unroll
  for (int i = 0; i < 2; ++i) {
    int qq = tid * 8 + i * 4096;
    int r1 = qq >> 8;
    int c1 = (qq & 255) ^ ((r1 & 7) << 3);
    gld16(W1T + (size_t)r1 * 256 + c1, w1c[0] + w * 512 + i * 4096);
    int r2 = qq >> 5;
    int c2 = (qq & 31) ^ ((r2 & 3) << 3);
    gld16(W2P + (size_t)r2 * 2048 + c2, w2c[0] + w * 512 + i * 4096);
  }

  // y A-fragments: wave owns 32 rows (rq*32 .. +31), 2 m-frags x 8 k-frags
  s8 yv[2][8];
#pragma unroll
  for (int mi = 0; mi < 2; ++mi) {
    int yrow = Mtile + rq * 32 + mi * 16 + c; if (yrow > M - 1) yrow = M - 1;
    const ushortT* yp = y + (size_t)yrow * 256 + g * 8;
#pragma unroll
    for (int ksi = 0; ksi < 8; ++ksi) yv[mi][ksi] = *(const s8*)(yp + ksi * 32);
  }

  float b2v[4];
#pragma unroll
  for (int ni = 0; ni < 4; ++ni) b2v[ni] = b2[nq * 64 + ni * 16 + c];

  f4 acc[4][4];
#pragma unroll
  for (int mi = 0; mi < 4; ++mi)
#pragma unroll
    for (int ni = 0; ni < 4; ++ni) acc[mi][ni] = 0.f;

  __syncthreads();   // chunk-0 weights + b1l resident (drains prestage vmcnt)

  const int fr = fh * 16 + c;   // f-row within chunk (0..31); fr&7 == c&7

  for (int chn = 0; chn < 64; ++chn) {
    const int b = chn & 1;
    const ushortT* w1b = w1c[b];
    const ushortT* w2b = w2c[b];

    // A: prefetch next chunk into the idle buffers (stays in flight to E)
    if (chn + 1 < 64) {
      const size_t f1 = (size_t)(chn + 1) * 32 * 256;
      const int k1 = (chn + 1) * 32;
#pragma unroll
      for (int i = 0; i < 2; ++i) {
        int qq = tid * 8 + i * 4096;
        int r1 = qq >> 8;
        int c1 = (qq & 255) ^ ((r1 & 7) << 3);
        gld16(W1T + f1 + (size_t)r1 * 256 + c1, w1c[b ^ 1] + w * 512 + i * 4096);
        int r2 = qq >> 5;
        int c2 = (qq & 31) ^ ((r2 & 3) << 3);
        gld16(W2P + (size_t)r2 * 2048 + k1 + c2, w2c[b ^ 1] + w * 512 + i * 4096);
      }
    }

    // B: h chunk = relu(y @ W1[:, fc:fc+32] + b1); wave does 32 rows x 16 f
    f4 sc[2];
    sc[0] = 0.f; sc[1] = 0.f;
#pragma unroll
    for (int ksi = 0; ksi < 8; ++ksi) {
      s8 wf = *(const s8*)(w1b + fr * 256 + ((ksi * 32 + g * 8) ^ ((c & 7) << 3)));
      sc[0] = __builtin_amdgcn_mfma_f32_16x16x32_bf16(yv[0][ksi], wf, sc[0], 0, 0, 0);
      sc[1] = __builtin_amdgcn_mfma_f32_16x16x32_bf16(yv[1][ksi], wf, sc[1], 0, 0, 0);
    }
    {
      float bv = bf2f(b1l[chn * 32 + fr]);
#pragma unroll
      for (int mi = 0; mi < 2; ++mi)
#pragma unroll
        for (int r = 0; r < 4; ++r) sc[mi][r] = fmaxf(sc[mi][r] + bv, 0.f);
    }
    // phi32-pack: packed col = c*2 + fh -> b16 writes (2-way banks, free)
#pragma unroll
    for (int mi = 0; mi < 2; ++mi)
#pragma unroll
      for (int r = 0; r < 4; ++r)
        hs[(rq * 32 + mi * 16 + g * 4 + r) * HSTR3 + c * 2 + fh] = f2bf(sc[mi][r]);

    // C: h visible to all waves; prefetch vmcnt NOT drained here
    asm volatile("s_waitcnt lgkmcnt(0)" ::: "memory");
    __builtin_amdgcn_s_barrier();
    __builtin_amdgcn_sched_barrier(0);

    // D: out += h @ W2[fc:fc+32, :]; wave = 64 rows x 64 cols, acc[4][4]
    {
      s8 pf[4];
#pragma unroll
      for (int mi = 0; mi < 4; ++mi)
        pf[mi] = *(const s8*)(hs + (mq2 * 64 + mi * 16 + c) * HSTR3 + g * 8);
#pragma unroll
      for (int ni = 0; ni < 4; ++ni) {
        int n = nq * 64 + ni * 16 + c;
        s8 w2f = *(const s8*)(w2b + n * 32 + ((g * 8) ^ ((n & 3) << 3)));
#pragma unroll
        for (int mi = 0; mi < 4; ++mi)
          acc[mi][ni] = __builtin_amdgcn_mfma_f32_16x16x32_bf16(pf[mi], w2f, acc[mi][ni], 0, 0, 0);
      }
    }

    // E: drain prefetch; all hs/w2c reads done before next chunk overwrites
    asm volatile("s_waitcnt vmcnt(0) lgkmcnt(0)" ::: "memory");
    __builtin_amdgcn_s_barrier();
    __builtin_amdgcn_sched_barrier(0);
  }

  // epilogue: + b2, fp32 store
#pragma unroll
  for (int mi = 0; mi < 4; ++mi) {
#pragma unroll
    for (int r = 0; r < 4; ++r) {
      int grow = Mtile + mq2 * 64 + mi * 16 + g * 4 + r;
      if (grow < M) {
#pragma unroll
        for (int ni = 0; ni < 4; ++ni)
          outp[(size_t)grow * 256 + nq * 64 + ni * 16 + c] = acc[mi][ni][r] + b2v[ni];
      }
    }
  }
}

// ---------- fused residual-add + LayerNorm (D=256), one wave per row ----------
template <typename RT, typename VT, typename OT>
__global__ __launch_bounds__(256) void add_ln(
    const RT* __restrict__ res, const VT* __restrict__ val,
    const float* __restrict__ g, const float* __restrict__ beta,
    OT* __restrict__ out, int Mrows)
{
  int row = blockIdx.x * 4 + (threadIdx.x >> 6);
  int lane = threadIdx.x & 63;
  if (row >= Mrows) return;
  float x[4];
  {
    float rvf[4], vvf[4];
    if constexpr (sizeof(RT) == 2) {
      us4 rv = ((const us4*)((const ushortT*)res + (size_t)row * 256))[lane];
      rvf[0]=bf2f(rv[0]); rvf[1]=bf2f(rv[1]); rvf[2]=bf2f(rv[2]); rvf[3]=bf2f(rv[3]);
    } else {
      f4 rv = ((const f4*)((const float*)res + (size_t)row * 256))[lane];
      rvf[0]=rv[0]; rvf[1]=rv[1]; rvf[2]=rv[2]; rvf[3]=rv[3];
    }
    if constexpr (sizeof(VT) == 2) {
      us4 vv = ((const us4*)((const ushortT*)val + (size_t)row * 256))[lane];
      vvf[0]=bf2f(vv[0]); vvf[1]=bf2f(vv[1]); vvf[2]=bf2f(vv[2]); vvf[3]=bf2f(vv[3]);
    } else {
      f4 vv = ((const f4*)((const float*)val + (size_t)row * 256))[lane];
      vvf[0]=vv[0]; vvf[1]=vv[1]; vvf[2]=vv[2]; vvf[3]=vv[3];
    }
#pragma unroll
    for (int j = 0; j < 4; j++) x[j] = rvf[j] + vvf[j];
  }
  float s1 = x[0] + x[1] + x[2] + x[3];
  float s2 = x[0]*x[0] + x[1]*x[1] + x[2]*x[2] + x[3]*x[3];
#pragma unroll
  for (int off = 32; off; off >>= 1) {
    s1 += __shfl_xor(s1, off);
    s2 += __shfl_xor(s2, off);
  }
  float mean = s1 * (1.f / 256.f);
  float var  = s2 * (1.f / 256.f) - mean * mean;
  float rstd = rsqrtf(var + 1e-5f);
  f4 gv = ((const f4*)g)[lane], bv = ((const f4*)beta)[lane];
  if constexpr (sizeof(OT) == 2) {
    us4 o;
#pragma unroll
    for (int j = 0; j < 4; j++)
      o[j] = f2bf((x[j] - mean) * rstd * gv[j] + bv[j]);
    ((us4*)((ushortT*)out + (size_t)row * 256))[lane] = o;
  } else {
    f4 o;
#pragma unroll
    for (int j = 0; j < 4; j++)
      o[j] = (x[j] - mean) * rstd * gv[j] + bv[j];
    ((f4*)((float*)out + (size_t)row * 256))[lane] = o;
  }
}

// ---------- host ----------
extern "C" void kernel_launch(void* const* d_in, const int* in_sizes, int n_in,
                              void* d_out, int out_size, void* d_ws, size_t ws_size,
                              hipStream_t stream) {
  const float* x   = (const float*)d_in[0];
  const float* Wq  = (const float*)d_in[1];
  const float* bq  = (const float*)d_in[2];
  const float* Wk  = (const float*)d_in[3];
  const float* bk  = (const float*)d_in[4];
  const float* Wv  = (const float*)d_in[5];
  const float* bv  = (const float*)d_in[6];
  const float* Wo  = (const float*)d_in[7];
  const float* bo  = (const float*)d_in[8];
  const float* W1  = (const float*)d_in[9];
  const float* b1  = (const float*)d_in[10];
  const float* W2  = (const float*)d_in[11];
  const float* b2  = (const float*)d_in[12];
  const float* g1  = (const float*)d_in[13];
  const float* be1 = (const float*)d_in[14];
  const float* g2  = (const float*)d_in[15];
  const float* be2 = (const float*)d_in[16];
  float* outp = (float*)d_out;

  const int M = 16 * 12 * 325;   // 62400 rows
  const int D = 256;

  // ws layout (shorts): weights+bias | kb | vb
  ushortT* ws    = (ushortT*)d_ws;
  ushortT* WqkvT = ws;                         // 768x256
  ushortT* WoT   = ws + 196608;                // 256x256
  ushortT* W1T   = ws + 262144;                // 2048x256
  ushortT* W2P   = ws + 786432;                // 256x2048 (phi32-permuted k)
  float*   bqkv  = (float*)(ws + 1310720);     // 768 fp32
  ushortT* kb    = ws + 2097152;               // 16M sh = 32 MB
  ushortT* vb    = kb + 16777216;              // 16M sh = 32 MB
  ushortT* qb = (ushortT*)d_out;
  ushortT* xb = qb + (size_t)M * D;            // bf16 x (upper half of d_out)
  ushortT* ob = kb;                            // Wo out (k dead after attn)
  ushortT* y1 = vb;                            // LN1 out (v dead after attn)

  dim3 blk(256);

  prep<<<PREP_BLOCKS, blk, 0, stream>>>(x, Wq, Wk, Wv, Wo, W1, W2, bq, bk, bv,
                                        xb, WqkvT, WoT, W1T, W2P, bqkv);

  int mt = (M + BM - 1) / BM;   // 488
  const float qscale = 0.17677669529663687f;   // 1/sqrt(32), folded into Q

  gemm_async<ushortT><<<dim3(768 / BN, mt), blk, 0, stream>>>(
      xb, WqkvT, bqkv, qb, kb, vb, M, 768, D, 0, 1, qscale);

  attn_mfma<<<dim3(192 * 8), blk, 0, stream>>>(qb, kb, vb, qb);

  gemm_async<ushortT><<<dim3(D / BN, mt), blk, 0, stream>>>(
      qb, WoT, bo, ob, ob, ob, M, D, D, 0, 0, 1.f);

  add_ln<float, ushortT, ushortT><<<dim3((M + 3) / 4), blk, 0, stream>>>(x, ob, g1, be1, y1, M);

  ffn_fused<<<dim3((M + 127) / 128), dim3(512), 0, stream>>>(
      y1, W1T, b1, W2P, b2, outp, M);

  add_ln<ushortT, float, float><<<dim3((M + 3) / 4), blk, 0, stream>>>(y1, outp, g2, be2, outp, M);
}

// Round 5
// 479.332 us; speedup vs baseline: 1.5678x; 1.5678x over previous
//
#include <hip/hip_runtime.h>

typedef unsigned short ushortT;
typedef unsigned short us2 __attribute__((ext_vector_type(2)));
typedef unsigned short us4 __attribute__((ext_vector_type(4)));
typedef short s4 __attribute__((ext_vector_type(4)));
typedef short s8 __attribute__((ext_vector_type(8)));
typedef float f4 __attribute__((ext_vector_type(4)));

__device__ __forceinline__ float bf2f(ushortT u) {
  union { unsigned u; float f; } x; x.u = ((unsigned)u) << 16; return x.f;
}
__device__ __forceinline__ ushortT f2bf(float f) {
  union { float f; unsigned u; } x; x.f = f;
  unsigned r = x.u + 0x7fffu + ((x.u >> 16) & 1u);
  return (ushortT)(r >> 16);
}
__device__ __forceinline__ ushortT bftrunc(float f) {
  union { float f; unsigned u; } x; x.f = f;
  return (ushortT)(x.u >> 16);
}
__device__ __forceinline__ s4 lo4(s8 v) { return __builtin_shufflevector(v, v, 0, 1, 2, 3); }
__device__ __forceinline__ s4 hi4(s8 v) { return __builtin_shufflevector(v, v, 4, 5, 6, 7); }
__device__ __forceinline__ s8 cat(s4 a, s4 b) { return __builtin_shufflevector(a, b, 0, 1, 2, 3, 4, 5, 6, 7); }

// async global->LDS, 16B per lane; lds dest must be wave-uniform base (lane*16 implicit)
__device__ __forceinline__ void gld16(const ushortT* g, ushortT* l) {
  __builtin_amdgcn_global_load_lds(
      (const __attribute__((address_space(1))) void*)g,
      (__attribute__((address_space(3))) void*)l, 16, 0, 0);
}

// ---------- prep: x fp32->bf16, weight transposes (concat QKV), bias concat ----------
// W2 is stored phi32-permuted along K (phi(t*16+c)=c*2+t within each 32-chunk)
// so the fused FFN can consume h packed with the same permutation
// (contraction-invariant; identical to attn's V^T pcol trick).
#define CONV_BLOCKS 15600   // 62400*256/4/256
__global__ void prep(const float* __restrict__ x,
                     const float* __restrict__ Wq, const float* __restrict__ Wk,
                     const float* __restrict__ Wv, const float* __restrict__ Wo,
                     const float* __restrict__ W1, const float* __restrict__ W2,
                     const float* __restrict__ bq, const float* __restrict__ bk,
                     const float* __restrict__ bv,
                     ushortT* __restrict__ xb, ushortT* __restrict__ WqkvT,
                     ushortT* __restrict__ WoT, ushortT* __restrict__ W1T,
                     ushortT* __restrict__ W2P, float* __restrict__ bqkv)
{
  if (blockIdx.x < CONV_BLOCKS) {
    size_t base = ((size_t)blockIdx.x * 256 + threadIdx.x) * 4;
    f4 v = *(const f4*)(x + base);
    us4 o; o[0]=f2bf(v[0]); o[1]=f2bf(v[1]); o[2]=f2bf(v[2]); o[3]=f2bf(v[3]);
    *(us4*)(xb + base) = o;
    return;
  }
  long e = (long)(blockIdx.x - CONV_BLOCKS) * 256 + threadIdx.x;
  if (e < 196608) {                       // Wq|Wk|Wv -> WqkvT (768x256)
    int seg = e >> 16; int p = e & 65535; int r = p >> 8, c = p & 255;
    const float* W = seg == 0 ? Wq : (seg == 1 ? Wk : Wv);
    WqkvT[(size_t)(seg * 256 + c) * 256 + r] = f2bf(W[p]);
  } else if (e < 262144) {                // Wo -> WoT (256x256)
    int p = e - 196608; int r = p >> 8, c = p & 255;
    WoT[(size_t)c * 256 + r] = f2bf(Wo[p]);
  } else if (e < 786432) {                // W1 (256x2048) -> W1T (2048x256)
    int p = e - 262144; int r = p >> 11, c = p & 2047;
    W1T[(size_t)c * 256 + r] = f2bf(W1[p]);
  } else if (e < 1310720) {               // W2 (2048x256) -> W2P (256x2048, phi32 on k)
    int p = e - 786432; int r = p >> 8, c = p & 255;
    int rp = (r & ~31) | ((r & 15) << 1) | ((r >> 4) & 1);
    W2P[(size_t)c * 2048 + rp] = f2bf(W2[p]);
  } else {                                // bq|bk|bv -> bqkv (768 fp32)
    int p = (int)(e - 1310720);
    const float* b = (p >> 8) == 0 ? bq : ((p >> 8) == 1 ? bk : bv);
    bqkv[p] = b[p & 255];
  }
}
#define PREP_BLOCKS (CONV_BLOCKS + 5123)

// ---------- GEMM, 2-deep dbuf pipeline w/ counted vmcnt (T3/T4-minimal) ----------
#define BM 128
#define BN 128
#define BK 32

template <typename CT>
__global__ __launch_bounds__(256, 4) void gemm_async(
    const ushortT* __restrict__ A, const ushortT* __restrict__ Bt,
    const float* __restrict__ bias,
    CT* __restrict__ O0, CT* __restrict__ O1, CT* __restrict__ O2,
    int M, int N, int K, int relu, int route, float s0)
{
  __shared__ ushortT As[2][BM * BK];
  __shared__ ushortT Bs[2][BN * BK];
  const int tileN = blockIdx.x * BN;
  const int tileM = blockIdx.y * BM;
  const int tid  = threadIdx.x;
  const int wave = tid >> 6, lane = tid & 63;
  const int wm = (wave >> 1) * 64, wn = (wave & 1) * 64;
  const int lrow = lane & 15;
  const int kq = (lane >> 4) * 8;
  const int crow0 = (lane >> 4) * 4;
  const int ccol  = lane & 15;

  const int srow = wave * 16 + (lane >> 2);
  const int scol = (lane & 3) * 8;
  int ar0 = tileM + srow;        if (ar0 > M - 1) ar0 = M - 1;
  int ar1 = tileM + 64 + srow;   if (ar1 > M - 1) ar1 = M - 1;
  const ushortT* ap0 = A + (size_t)ar0 * K + scol;
  const ushortT* ap1 = A + (size_t)ar1 * K + scol;
  const ushortT* bp0 = Bt + (size_t)(tileN + srow) * K + scol;
  const ushortT* bp1 = Bt + (size_t)(tileN + 64 + srow) * K + scol;
  const int d0 = wave * 512;        // wave-uniform LDS dest offsets
  const int d1 = 2048 + wave * 512;

  // bias preload BEFORE any staging; keep-alive forces retire so in-loop
  // vmcnt counting sees only gld16 ops.
  float bvv[4];
#pragma unroll
  for (int ni = 0; ni < 4; ni++) bvv[ni] = bias[tileN + wn + ni * 16 + ccol];
  asm volatile("" :: "v"(bvv[0]), "v"(bvv[1]), "v"(bvv[2]), "v"(bvv[3]));

  f4 acc[4][4];
#pragma unroll
  for (int i = 0; i < 4; i++)
#pragma unroll
    for (int j = 0; j < 4; j++) acc[i][j] = 0.f;

  // prologue: stage tiles 0 and 1
  gld16(ap0, As[0] + d0); gld16(ap1, As[0] + d1);
  gld16(bp0, Bs[0] + d0); gld16(bp1, Bs[0] + d1);
  ap0 += BK; ap1 += BK; bp0 += BK; bp1 += BK;
  if (BK < K) {
    gld16(ap0, As[1] + d0); gld16(ap1, As[1] + d1);
    gld16(bp0, Bs[1] + d0); gld16(bp1, Bs[1] + d1);
    ap0 += BK; ap1 += BK; bp0 += BK; bp1 += BK;
  }

  int cur = 0;
  for (int k0 = 0; k0 < K; k0 += BK, cur ^= 1) {
    if (k0 + BK < K) asm volatile("s_waitcnt vmcnt(4)" ::: "memory");
    else             asm volatile("s_waitcnt vmcnt(0)" ::: "memory");
    __builtin_amdgcn_s_barrier();
    __builtin_amdgcn_sched_barrier(0);

    s8 af[4], bfr[4];
#pragma unroll
    for (int mi = 0; mi < 4; mi++)
      af[mi] = *(const s8*)(&As[cur][(wm + mi * 16 + lrow) * BK + kq]);
#pragma unroll
    for (int ni = 0; ni < 4; ni++)
      bfr[ni] = *(const s8*)(&Bs[cur][(wn + ni * 16 + lrow) * BK + kq]);
#pragma unroll
    for (int mi = 0; mi < 4; mi++)
#pragma unroll
      for (int ni = 0; ni < 4; ni++)
        acc[mi][ni] = __builtin_amdgcn_mfma_f32_16x16x32_bf16(af[mi], bfr[ni], acc[mi][ni], 0, 0, 0);

    __builtin_amdgcn_s_barrier();   // all waves done reading buf cur
    __builtin_amdgcn_sched_barrier(0);
    if (k0 + 2 * BK < K) {          // restage into the buffer just consumed
      gld16(ap0, As[cur] + d0); gld16(ap1, As[cur] + d1);
      gld16(bp0, Bs[cur] + d0); gld16(bp1, Bs[cur] + d1);
      ap0 += BK; ap1 += BK; bp0 += BK; bp1 += BK;
    }
  }

  CT* dst; int col0, ostride;
  float oscale = 1.f;
  if (route) {
    int seg = tileN >> 8;
    dst = seg == 0 ? O0 : (seg == 1 ? O1 : O2);
    col0 = tileN & 255; ostride = 256;
    if (seg == 0) oscale = s0;
  } else {
    dst = O0; col0 = tileN; ostride = N;
  }
#pragma unroll
  for (int mi = 0; mi < 4; mi++) {
#pragma unroll
    for (int ni = 0; ni < 4; ni++) {
      int lcol = wn + ni * 16 + ccol;
#pragma unroll
      for (int r = 0; r < 4; r++) {
        int grow = tileM + wm + mi * 16 + crow0 + r;
        if (grow < M) {
          float v = (acc[mi][ni][r] + bvv[ni]) * oscale;
          if (relu) v = fmaxf(v, 0.f);
          if constexpr (sizeof(CT) == 2)
            dst[(size_t)grow * ostride + col0 + lcol] = f2bf(v);
          else
            dst[(size_t)grow * ostride + col0 + lcol] = v;
        }
      }
    }
  }
}

// ---------- MFMA attention, shuffle-free softmax ----------
#define NQ 325
#define NPAD 384
#define KSTR 36      // 72B rows: dword-stride 18 -> 4-way banks, b64-aligned
#define VSTR 388     // 776B rows: dword-stride 194 -> 4-way banks, b64-aligned
#define PSTR 72      // 144B rows: b128-aligned A-frag reads

__global__ __launch_bounds__(256, 2) void attn_mfma(
    const ushortT* __restrict__ q, const ushortT* __restrict__ k,
    const ushortT* __restrict__ v, ushortT* __restrict__ out)
{
  __shared__ ushortT ks[NPAD * KSTR];        // 27648 B
  __shared__ ushortT vt[32 * VSTR];          // 24832 B
  __shared__ ushortT ps[4 * 16 * PSTR];      //  9216 B  (61696 total -> 2 blocks/CU)
  const int bs = blockIdx.x >> 3;
  const int h  = blockIdx.x & 7;
  const size_t rowbase = (size_t)bs * NQ;
  const int hcol = h * 32;
  const int tid = threadIdx.x;
  const int wave = tid >> 6, lane = tid & 63;
  const int g = lane >> 4;
  const int c = lane & 15;

  for (int idx = tid; idx < NPAD * 4; idx += 256) {
    int row = idx >> 2, part = idx & 3;
    s8 kv = 0, vv = 0;
    if (row < NQ) {
      kv = *(const s8*)(k + (rowbase + row) * 256 + hcol + part * 8);
      vv = *(const s8*)(v + (rowbase + row) * 256 + hcol + part * 8);
    }
    *(s4*)(ks + row * KSTR + part * 8)     = lo4(kv);
    *(s4*)(ks + row * KSTR + part * 8 + 4) = hi4(kv);
    int pcol = (row & ~63) | ((row & 15) << 2) | ((row >> 4) & 3);
#pragma unroll
    for (int j = 0; j < 8; j++)
      vt[(part * 8 + j) * VSTR + pcol] = (ushortT)vv[j];
  }
  __syncthreads();

  s8 ones;
#pragma unroll
  for (int j = 0; j < 8; j++) ones[j] = (short)0x3F80;   // bf16 1.0

  ushortT* psw = ps + wave * 16 * PSTR;

  for (int strip = wave; strip < 21; strip += 4) {
    const int m0 = strip * 16;
    s8 qf = 0;
    {
      int qrow = m0 + c;
      if (qrow < NQ) qf = *(const s8*)(q + (rowbase + qrow) * 256 + hcol + g * 8);
    }
    f4 ov0 = 0.f, ov1 = 0.f, ovs = 0.f;

    for (int ch = 0; ch < 6; ++ch) {
      const int nbase = ch * 64;
      f4 sc[4];
#pragma unroll
      for (int t = 0; t < 4; ++t) {
        const ushortT* kr = ks + (nbase + t * 16 + c) * KSTR + g * 8;
        s8 kf = cat(*(const s4*)kr, *(const s4*)(kr + 4));
        f4 z = 0.f;
        sc[t] = __builtin_amdgcn_mfma_f32_16x16x32_bf16(qf, kf, z, 0, 0, 0);
      }
#pragma unroll
      for (int t = 0; t < 4; ++t)
#pragma unroll
        for (int r = 0; r < 4; ++r)
          sc[t][r] = __expf(sc[t][r]);
      if (ch == 5) {
#pragma unroll
        for (int t = 0; t < 4; ++t) {
          bool valid = (t == 0) && (c < 5);   // keys 320..324
#pragma unroll
          for (int r = 0; r < 4; ++r)
            if (!valid) sc[t][r] = 0.f;
        }
      }
#pragma unroll
      for (int r = 0; r < 4; ++r) {
        us4 pw;
#pragma unroll
        for (int t = 0; t < 4; ++t) pw[t] = bftrunc(sc[t][r]);
        *(us4*)(psw + (g * 4 + r) * PSTR + c * 4) = pw;
      }
#pragma unroll
      for (int kt = 0; kt < 2; ++kt) {
        s8 pf = *(const s8*)(psw + c * PSTR + kt * 32 + g * 8);
        ovs = __builtin_amdgcn_mfma_f32_16x16x32_bf16(pf, ones, ovs, 0, 0, 0);
        const ushortT* vr0 = vt + c * VSTR + nbase + kt * 32 + g * 8;
        const ushortT* vr1 = vt + (16 + c) * VSTR + nbase + kt * 32 + g * 8;
        s8 vf0 = cat(*(const s4*)vr0, *(const s4*)(vr0 + 4));
        s8 vf1 = cat(*(const s4*)vr1, *(const s4*)(vr1 + 4));
        ov0 = __builtin_amdgcn_mfma_f32_16x16x32_bf16(pf, vf0, ov0, 0, 0, 0);
        ov1 = __builtin_amdgcn_mfma_f32_16x16x32_bf16(pf, vf1, ov1, 0, 0, 0);
      }
    }
#pragma unroll
    for (int r = 0; r < 4; ++r) {
      int gm = m0 + g * 4 + r;
      if (gm < NQ) {
        float inv = 1.f / ovs[r];
        out[(rowbase + gm) * 256 + hcol + c]      = f2bf(ov0[r] * inv);
        out[(rowbase + gm) * 256 + hcol + 16 + c] = f2bf(ov1[r] * inv);
      }
    }
  }
}

// ---------- fused FFN v5: producer/consumer wave specialization ----------
// R4 post-mortem: VGPR cap 128 with yv(64)+acc(64)+transients in EVERY wave
// -> spill -> 1.36 GB scratch FETCH. Fix: 1024-thr blocks, 8 producer waves
// (h = relu(y@W1+b1), hold yv only) + 8 consumer waves (out += h@W2, hold acc
// only), in DISJOINT branches with separate loops so yv and acc share physical
// registers (~105 peak/path < 128 @ launch_bounds(1024,4)).
// FCH=32, everything double-buffered: LDS = 2x16(W1)+2x16(W2)+2x8(hs) = 80 KB
// -> 16 waves/CU = 4 waves/SIMD even at 1 block/CU. ONE __syncthreads per step
// (its vmcnt(0) drain lands a full step after the stage issues -> hidden);
// producer step i runs CONCURRENTLY with consumer step i-1.
// h packed phi32 (col = c*2 + fh); W2P pre-permuted phi32 at prep -> invariant.
__global__ __launch_bounds__(1024, 4) void ffn_fused(
    const ushortT* __restrict__ y, const ushortT* __restrict__ W1T,
    const float* __restrict__ b1, const ushortT* __restrict__ W2P,
    const float* __restrict__ b2, float* __restrict__ outp, int M)
{
  __shared__ ushortT w1c[2][32 * 256];    // 2 x 16 KB  [f-row][k]
  __shared__ ushortT w2c[2][256 * 32];    // 2 x 16 KB  [n-row][k-packed]
  __shared__ ushortT hs[2][128 * 32];     // 2 x  8 KB  [row][f-packed]

  const int tid = threadIdx.x;
  const int w = tid >> 6, lane = tid & 63;
  const int g = lane >> 4, c = lane & 15;
  const int Mtile = blockIdx.x * 128;

  if (w < 8) {
    // ---------------- producers: h(i) -> hs[i&1] ----------------
    const int rq = w >> 1, fh = w & 1;
    const int fr = fh * 16 + c;                 // f-row within chunk (0..31)
    // per-thread staging source offsets (constant across chunks)
    const int qa = tid * 8, qb = tid * 8 + 4096;
    const int ra = qa >> 8, rb = qb >> 8;
    const int sa = ra * 256 + ((qa & 255) ^ ((ra & 7) << 3));
    const int sb = rb * 256 + ((qb & 255) ^ ((rb & 7) << 3));

    // y A-fragments: wave owns 32 rows (rq*32 .. +31)
    s8 yv[2][8];
#pragma unroll
    for (int mi = 0; mi < 2; ++mi) {
      int yrow = Mtile + rq * 32 + mi * 16 + c; if (yrow > M - 1) yrow = M - 1;
      const ushortT* yp = y + (size_t)yrow * 256 + g * 8;
#pragma unroll
      for (int ksi = 0; ksi < 8; ++ksi) yv[mi][ksi] = *(const s8*)(yp + ksi * 32);
    }
    float bcur = b1[fr];                        // chunk-0 bias
    // prestage W1(0)
    gld16(W1T + sa, w1c[0] + w * 512);
    gld16(W1T + sb, w1c[0] + w * 512 + 4096);
    __syncthreads();

    float bnext = 0.f;
    for (int i = 0; i <= 64; ++i) {
      if (i < 64) {
        const ushortT* w1b = w1c[i & 1];
        if (i < 63) {                           // stage W1(i+1) + bias(i+1)
          const size_t fb = (size_t)(i + 1) * 8192;
          gld16(W1T + fb + sa, w1c[(i + 1) & 1] + w * 512);
          gld16(W1T + fb + sb, w1c[(i + 1) & 1] + w * 512 + 4096);
          bnext = b1[(i + 1) * 32 + fr];
        }
        f4 sc0 = 0.f, sc1 = 0.f;
#pragma unroll
        for (int ksi = 0; ksi < 8; ++ksi) {
          s8 wf = *(const s8*)(w1b + fr * 256 + ((ksi * 32 + g * 8) ^ ((c & 7) << 3)));
          sc0 = __builtin_amdgcn_mfma_f32_16x16x32_bf16(yv[0][ksi], wf, sc0, 0, 0, 0);
          sc1 = __builtin_amdgcn_mfma_f32_16x16x32_bf16(yv[1][ksi], wf, sc1, 0, 0, 0);
        }
        // bias + relu + phi32-pack (packed col = c*2 + fh)
        ushortT* hw = hs[i & 1] + (rq * 32 + g * 4) * 32 + c * 2 + fh;
#pragma unroll
        for (int r = 0; r < 4; ++r) {
          hw[r * 32]        = f2bf(fmaxf(sc0[r] + bcur, 0.f));
          hw[(16 + r) * 32] = f2bf(fmaxf(sc1[r] + bcur, 0.f));
        }
        bcur = bnext;
      }
      __syncthreads();
    }
  } else {
    // ---------------- consumers: out += h(i-1) @ W2(i-1) ----------------
    const int ow = w - 8;
    const int mq2 = ow >> 2, nq = ow & 3;       // 64 rows x 64 cols per wave
    const int qa = (tid - 512) * 8, qb = (tid - 512) * 8 + 4096;
    const int ra = qa >> 5, rb = qb >> 5;
    const int sa = ra * 2048 + ((qa & 31) ^ ((ra & 3) << 3));
    const int sb = rb * 2048 + ((qb & 31) ^ ((rb & 3) << 3));

    float b2v[4];
#pragma unroll
    for (int ni = 0; ni < 4; ++ni) b2v[ni] = b2[nq * 64 + ni * 16 + c];

    f4 acc[4][4];
#pragma unroll
    for (int mi = 0; mi < 4; ++mi)
#pragma unroll
      for (int ni = 0; ni < 4; ++ni) acc[mi][ni] = 0.f;

    // prestage W2(0)
    gld16(W2P + sa, w2c[0] + ow * 512);
    gld16(W2P + sb, w2c[0] + ow * 512 + 4096);
    __syncthreads();

    for (int i = 0; i <= 64; ++i) {
      if (i >= 1) {
        if (i <= 63) {                          // stage W2(i) for step i+1
          gld16(W2P + i * 32 + sa, w2c[i & 1] + ow * 512);
          gld16(W2P + i * 32 + sb, w2c[i & 1] + ow * 512 + 4096);
        }
        const ushortT* hb  = hs[(i - 1) & 1];
        const ushortT* w2b = w2c[(i - 1) & 1];
        s8 pf[4];
#pragma unroll
        for (int mi = 0; mi < 4; ++mi)
          pf[mi] = *(const s8*)(hb + (mq2 * 64 + mi * 16 + c) * 32 + g * 8);
#pragma unroll
        for (int ni = 0; ni < 4; ++ni) {
          int n = nq * 64 + ni * 16 + c;
          s8 w2f = *(const s8*)(w2b + n * 32 + ((g * 8) ^ ((n & 3) << 3)));
#pragma unroll
          for (int mi = 0; mi < 4; ++mi)
            acc[mi][ni] = __builtin_amdgcn_mfma_f32_16x16x32_bf16(pf[mi], w2f, acc[mi][ni], 0, 0, 0);
        }
      }
      __syncthreads();
    }

    // epilogue: + b2, fp32 store
#pragma unroll
    for (int mi = 0; mi < 4; ++mi) {
#pragma unroll
      for (int r = 0; r < 4; ++r) {
        int grow = Mtile + mq2 * 64 + mi * 16 + g * 4 + r;
        if (grow < M) {
#pragma unroll
          for (int ni = 0; ni < 4; ++ni)
            outp[(size_t)grow * 256 + nq * 64 + ni * 16 + c] = acc[mi][ni][r] + b2v[ni];
        }
      }
    }
  }
}

// ---------- fused residual-add + LayerNorm (D=256), one wave per row ----------
template <typename RT, typename VT, typename OT>
__global__ __launch_bounds__(256) void add_ln(
    const RT* __restrict__ res, const VT* __restrict__ val,
    const float* __restrict__ g, const float* __restrict__ beta,
    OT* __restrict__ out, int Mrows)
{
  int row = blockIdx.x * 4 + (threadIdx.x >> 6);
  int lane = threadIdx.x & 63;
  if (row >= Mrows) return;
  float x[4];
  {
    float rvf[4], vvf[4];
    if constexpr (sizeof(RT) == 2) {
      us4 rv = ((const us4*)((const ushortT*)res + (size_t)row * 256))[lane];
      rvf[0]=bf2f(rv[0]); rvf[1]=bf2f(rv[1]); rvf[2]=bf2f(rv[2]); rvf[3]=bf2f(rv[3]);
    } else {
      f4 rv = ((const f4*)((const float*)res + (size_t)row * 256))[lane];
      rvf[0]=rv[0]; rvf[1]=rv[1]; rvf[2]=rv[2]; rvf[3]=rv[3];
    }
    if constexpr (sizeof(VT) == 2) {
      us4 vv = ((const us4*)((const ushortT*)val + (size_t)row * 256))[lane];
      vvf[0]=bf2f(vv[0]); vvf[1]=bf2f(vv[1]); vvf[2]=bf2f(vv[2]); vvf[3]=bf2f(vv[3]);
    } else {
      f4 vv = ((const f4*)((const float*)val + (size_t)row * 256))[lane];
      vvf[0]=vv[0]; vvf[1]=vv[1]; vvf[2]=vv[2]; vvf[3]=vv[3];
    }
#pragma unroll
    for (int j = 0; j < 4; j++) x[j] = rvf[j] + vvf[j];
  }
  float s1 = x[0] + x[1] + x[2] + x[3];
  float s2 = x[0]*x[0] + x[1]*x[1] + x[2]*x[2] + x[3]*x[3];
#pragma unroll
  for (int off = 32; off; off >>= 1) {
    s1 += __shfl_xor(s1, off);
    s2 += __shfl_xor(s2, off);
  }
  float mean = s1 * (1.f / 256.f);
  float var  = s2 * (1.f / 256.f) - mean * mean;
  float rstd = rsqrtf(var + 1e-5f);
  f4 gv = ((const f4*)g)[lane], bv = ((const f4*)beta)[lane];
  if constexpr (sizeof(OT) == 2) {
    us4 o;
#pragma unroll
    for (int j = 0; j < 4; j++)
      o[j] = f2bf((x[j] - mean) * rstd * gv[j] + bv[j]);
    ((us4*)((ushortT*)out + (size_t)row * 256))[lane] = o;
  } else {
    f4 o;
#pragma unroll
    for (int j = 0; j < 4; j++)
      o[j] = (x[j] - mean) * rstd * gv[j] + bv[j];
    ((f4*)((float*)out + (size_t)row * 256))[lane] = o;
  }
}

// ---------- host ----------
extern "C" void kernel_launch(void* const* d_in, const int* in_sizes, int n_in,
                              void* d_out, int out_size, void* d_ws, size_t ws_size,
                              hipStream_t stream) {
  const float* x   = (const float*)d_in[0];
  const float* Wq  = (const float*)d_in[1];
  const float* bq  = (const float*)d_in[2];
  const float* Wk  = (const float*)d_in[3];
  const float* bk  = (const float*)d_in[4];
  const float* Wv  = (const float*)d_in[5];
  const float* bv  = (const float*)d_in[6];
  const float* Wo  = (const float*)d_in[7];
  const float* bo  = (const float*)d_in[8];
  const float* W1  = (const float*)d_in[9];
  const float* b1  = (const float*)d_in[10];
  const float* W2  = (const float*)d_in[11];
  const float* b2  = (const float*)d_in[12];
  const float* g1  = (const float*)d_in[13];
  const float* be1 = (const float*)d_in[14];
  const float* g2  = (const float*)d_in[15];
  const float* be2 = (const float*)d_in[16];
  float* outp = (float*)d_out;

  const int M = 16 * 12 * 325;   // 62400 rows
  const int D = 256;

  // ws layout (shorts): weights+bias | kb | vb
  ushortT* ws    = (ushortT*)d_ws;
  ushortT* WqkvT = ws;                         // 768x256
  ushortT* WoT   = ws + 196608;                // 256x256
  ushortT* W1T   = ws + 262144;                // 2048x256
  ushortT* W2P   = ws + 786432;                // 256x2048 (phi32-permuted k)
  float*   bqkv  = (float*)(ws + 1310720);     // 768 fp32
  ushortT* kb    = ws + 2097152;               // 16M sh = 32 MB
  ushortT* vb    = kb + 16777216;              // 16M sh = 32 MB
  ushortT* qb = (ushortT*)d_out;
  ushortT* xb = qb + (size_t)M * D;            // bf16 x (upper half of d_out)
  ushortT* ob = kb;                            // Wo out (k dead after attn)
  ushortT* y1 = vb;                            // LN1 out (v dead after attn)

  dim3 blk(256);

  prep<<<PREP_BLOCKS, blk, 0, stream>>>(x, Wq, Wk, Wv, Wo, W1, W2, bq, bk, bv,
                                        xb, WqkvT, WoT, W1T, W2P, bqkv);

  int mt = (M + BM - 1) / BM;   // 488
  const float qscale = 0.17677669529663687f;   // 1/sqrt(32), folded into Q

  gemm_async<ushortT><<<dim3(768 / BN, mt), blk, 0, stream>>>(
      xb, WqkvT, bqkv, qb, kb, vb, M, 768, D, 0, 1, qscale);

  attn_mfma<<<dim3(192 * 8), blk, 0, stream>>>(qb, kb, vb, qb);

  gemm_async<ushortT><<<dim3(D / BN, mt), blk, 0, stream>>>(
      qb, WoT, bo, ob, ob, ob, M, D, D, 0, 0, 1.f);

  add_ln<float, ushortT, ushortT><<<dim3((M + 3) / 4), blk, 0, stream>>>(x, ob, g1, be1, y1, M);

  ffn_fused<<<dim3((M + 127) / 128), dim3(1024), 0, stream>>>(
      y1, W1T, b1, W2P, b2, outp, M);

  add_ln<ushortT, float, float><<<dim3((M + 3) / 4), blk, 0, stream>>>(y1, outp, g2, be2, outp, M);
}